// Round 1
// baseline (83.678 us; speedup 1.0000x reference)
//
#include <hip/hip_runtime.h>

#define O_DIM 32
#define Q_DIM 8
#define HW 32

__device__ __forceinline__ float sigmoidf(float v) {
    // 1/(1+exp(-v)); v_exp_f32 + v_rcp_f32, ~2ulp — far inside the 4.5e-3 threshold.
    return __builtin_amdgcn_rcpf(1.0f + __expf(-v));
}

// 4-input multilinear LUT interp over 16 corners; corner bit i <-> input s_i.
__device__ __forceinline__ float lut4(float s0, float s1, float s2, float s3,
                                      const float* __restrict__ W) {
    float a[8];
#pragma unroll
    for (int j = 0; j < 8; ++j) a[j] = fmaf(s3, W[j + 8] - W[j], W[j]);
#pragma unroll
    for (int j = 0; j < 4; ++j) a[j] = fmaf(s2, a[j + 4] - a[j], a[j]);
#pragma unroll
    for (int j = 0; j < 2; ++j) a[j] = fmaf(s1, a[j + 2] - a[j], a[j]);
    return fmaf(s0, a[1] - a[0], a[0]);
}

__global__ __launch_bounds__(256) void lt_conv_kernel(
    const float* __restrict__ x,   // [8,64,32,32]
    const float* __restrict__ w0,  // [32,18,16]
    const float* __restrict__ w1,  // [32,5,16]
    const float* __restrict__ w2,  // [32,2,16]
    const float* __restrict__ w3,  // [32,1,16]
    const int*   __restrict__ ci,  // [32,8]
    float*       __restrict__ out) // [8,32,32,32] (B,O,H,W)
{
    const int bid  = blockIdx.x;
    const int tile = bid & 3;          // 4 row-tiles of 8 rows
    const int b    = (bid >> 2) & 7;
    const int o    = bid >> 5;         // block-uniform -> scalar weight loads

    const int tid = threadIdx.x;
    const int wo  = tid & 31;
    const int ho  = tile * 8 + (tid >> 5);

    // ---- gather 8 channels x 3x3 patch, sigmoid -> s[72] (flat order q*9 + dy*3 + dx)
    float s[72];
#pragma unroll
    for (int q = 0; q < Q_DIM; ++q) {
        const int c = ci[o * Q_DIM + q];
        const float* xc = x + (size_t)(b * 64 + c) * (HW * HW);
#pragma unroll
        for (int dy = 0; dy < 3; ++dy) {
            const int y = ho + dy - 1;
            const bool yok = (unsigned)y < (unsigned)HW;
#pragma unroll
            for (int dx = 0; dx < 3; ++dx) {
                const int xx = wo + dx - 1;
                const bool ok = yok && ((unsigned)xx < (unsigned)HW);
                const float v = ok ? xc[y * HW + xx] : 0.0f;  // zero-pad; sigmoid(0)=0.5 == ref pad
                s[q * 9 + dy * 3 + dx] = sigmoidf(v);
            }
        }
    }

    // ---- level 0: 18 LUTs over s[4l..4l+3], then sigmoid
    const float* W0 = w0 + o * 18 * 16;
    float t[18];
#pragma unroll
    for (int l = 0; l < 18; ++l)
        t[l] = sigmoidf(lut4(s[4*l], s[4*l+1], s[4*l+2], s[4*l+3], W0 + l*16));

    // ---- level 1: 5 LUTs (inputs 18 padded to 20 with 0.5), then sigmoid
    const float* W1 = w1 + o * 5 * 16;
    float u[5];
#pragma unroll
    for (int l = 0; l < 4; ++l)
        u[l] = sigmoidf(lut4(t[4*l], t[4*l+1], t[4*l+2], t[4*l+3], W1 + l*16));
    u[4] = sigmoidf(lut4(t[16], t[17], 0.5f, 0.5f, W1 + 4*16));

    // ---- level 2: 2 LUTs (inputs 5 padded to 8), then sigmoid
    const float* W2 = w2 + o * 2 * 16;
    const float v0 = sigmoidf(lut4(u[0], u[1], u[2], u[3], W2));
    const float v1 = sigmoidf(lut4(u[4], 0.5f, 0.5f, 0.5f, W2 + 16));

    // ---- level 3: final LUT (inputs 2 padded to 4), NO sigmoid
    const float* W3 = w3 + o * 16;
    const float r = lut4(v0, v1, 0.5f, 0.5f, W3);

    // out[b][o][ho][wo]
    out[((size_t)(b * O_DIM + o) * HW + ho) * HW + wo] = r;
}

extern "C" void kernel_launch(void* const* d_in, const int* in_sizes, int n_in,
                              void* d_out, int out_size, void* d_ws, size_t ws_size,
                              hipStream_t stream) {
    const float* x  = (const float*)d_in[0];
    const float* w0 = (const float*)d_in[1];
    const float* w1 = (const float*)d_in[2];
    const float* w2 = (const float*)d_in[3];
    const float* w3 = (const float*)d_in[4];
    const int*   ci = (const int*)d_in[5];
    float* out = (float*)d_out;

    dim3 grid(O_DIM * 8 * 4);  // o * b * row-tiles
    dim3 block(256);           // 8 rows x 32 cols
    lt_conv_kernel<<<grid, block, 0, stream>>>(x, w0, w1, w2, w3, ci, out);
}

// Round 2
// 80.709 us; speedup vs baseline: 1.0368x; 1.0368x over previous
//
#include <hip/hip_runtime.h>

typedef float v2f __attribute__((ext_vector_type(2)));

#define HW 32
#define QD 8

__device__ __forceinline__ float sigmoidf(float v) {
    // 1/(1+exp(-v)) via v_exp_f32 + v_rcp_f32; absmax vs np ref was 4.9e-4 in R0.
    return __builtin_amdgcn_rcpf(1.0f + __expf(-v));
}

__device__ __forceinline__ v2f sig2(v2f v) {
    v2f r; r.x = sigmoidf(v.x); r.y = sigmoidf(v.y); return r;
}

// 4-input multilinear LUT over 16 corners on a float2 (2 pixels at once).
// Corner bit i <-> input s[i]. Scalar weight subs are wave-uniform; the
// vector math lowers to v_pk_fma_f32 / v_pk_add_f32 (packed fp32).
__device__ __forceinline__ v2f lut4v(const v2f* s, const float* __restrict__ W) {
    v2f a[8];
#pragma unroll
    for (int j = 0; j < 8; ++j) {
        const float d = W[j + 8] - W[j];
        const v2f dv = {d, d}, wv = {W[j], W[j]};
        a[j] = __builtin_elementwise_fma(s[3], dv, wv);
    }
#pragma unroll
    for (int j = 0; j < 4; ++j) a[j] = __builtin_elementwise_fma(s[2], a[j + 4] - a[j], a[j]);
#pragma unroll
    for (int j = 0; j < 2; ++j) a[j] = __builtin_elementwise_fma(s[1], a[j + 2] - a[j], a[j]);
    return __builtin_elementwise_fma(s[0], a[1] - a[0], a[0]);
}

// One block per (o, b): 512 threads, each computes 2 vertically-adjacent pixels.
// stile[q][row][col]: sigmoid(x) for the 8 selected channels, 34x34 (1-halo,
// OOB = sigmoid(0) = 0.5 which matches the reference's post-sigmoid 0.5 pad).
__global__ __launch_bounds__(512, 4) void lt_conv_kernel(
    const float* __restrict__ x,   // [8,64,32,32]
    const float* __restrict__ w0,  // [32,18,16]
    const float* __restrict__ w1,  // [32,5,16]
    const float* __restrict__ w2,  // [32,2,16]
    const float* __restrict__ w3,  // [32,1,16]
    const int*   __restrict__ ci,  // [32,8]
    float*       __restrict__ out) // [8,32,32,32]
{
    const int o = blockIdx.x & 31;
    const int b = blockIdx.x >> 5;
    const int tid = threadIdx.x;

    __shared__ float stile[QD * 34 * 34];   // 36,992 B
    __shared__ int   ldsci[QD];

    if (tid < QD) ldsci[tid] = ci[o * QD + tid];
    __syncthreads();

    // ---- stage: sigmoid(x) for 8 channels, 34x34 with zero-pad halo
#pragma unroll
    for (int it = 0; it < 19; ++it) {
        const int idx = tid + it * 512;
        if (idx < QD * 34 * 34) {
            const int q   = idx / 1156;
            const int rem = idx - q * 1156;
            const int row = rem / 34;
            const int col = rem - row * 34;
            const int y = row - 1, xx = col - 1;
            float v = 0.0f;
            if ((unsigned)y < 32u && (unsigned)xx < 32u) {
                const int c = ldsci[q];
                v = x[(((size_t)b * 64 + c) * HW + y) * HW + xx];
            }
            stile[idx] = sigmoidf(v);
        }
    }
    __syncthreads();

    const int wo = tid & 31;        // output column
    const int r0 = (tid >> 5) * 2;  // output rows r0, r0+1

    // ---- level 0: 18 LUTs over the 72 patch values (flat = q*9 + dy*3 + dx).
    // Identical-address LDS loads between the two pixels CSE (rows shared).
    const float* W0 = w0 + o * 18 * 16;
    v2f t[18];
#pragma unroll
    for (int l = 0; l < 18; ++l) {
        v2f p[4];
#pragma unroll
        for (int j = 0; j < 4; ++j) {
            const int flat = 4 * l + j;
            const int q = flat / 9, k = flat - 9 * q;
            const int dy = k / 3, dx = k - 3 * dy;
            const float* base = stile + q * 1156 + (r0 + dy) * 34 + (wo + dx);
            p[j].x = base[0];
            p[j].y = base[34];
        }
        t[l] = sig2(lut4v(p, W0 + l * 16));
    }

    // ---- level 1: 5 LUTs (18 inputs padded to 20 with 0.5)
    const float* W1 = w1 + o * 5 * 16;
    const v2f h = {0.5f, 0.5f};
    v2f u[5];
#pragma unroll
    for (int l = 0; l < 4; ++l) u[l] = sig2(lut4v(t + 4 * l, W1 + l * 16));
    {
        v2f p[4] = {t[16], t[17], h, h};
        u[4] = sig2(lut4v(p, W1 + 4 * 16));
    }

    // ---- level 2: 2 LUTs (5 inputs padded to 8)
    const float* W2 = w2 + o * 2 * 16;
    const v2f vv0 = sig2(lut4v(u, W2));
    v2f p1[4] = {u[4], h, h, h};
    const v2f vv1 = sig2(lut4v(p1, W2 + 16));

    // ---- level 3: final LUT (2 inputs padded to 4), no sigmoid
    const float* W3 = w3 + o * 16;
    v2f p2[4] = {vv0, vv1, h, h};
    const v2f res = lut4v(p2, W3);

    float* op = out + (((size_t)b * 32 + o) * HW + r0) * HW + wo;
    op[0]  = res.x;
    op[HW] = res.y;
}

extern "C" void kernel_launch(void* const* d_in, const int* in_sizes, int n_in,
                              void* d_out, int out_size, void* d_ws, size_t ws_size,
                              hipStream_t stream) {
    const float* x  = (const float*)d_in[0];
    const float* w0 = (const float*)d_in[1];
    const float* w1 = (const float*)d_in[2];
    const float* w2 = (const float*)d_in[3];
    const float* w3 = (const float*)d_in[4];
    const int*   ci = (const int*)d_in[5];
    float* out = (float*)d_out;

    lt_conv_kernel<<<dim3(32 * 8), dim3(512), 0, stream>>>(x, w0, w1, w2, w3, ci, out);
}